// Round 7
// baseline (665.434 us; speedup 1.0000x reference)
//
#include <hip/hip_runtime.h>

// LIIF render, fully fused, fp16 MFMA. Round 6: A-only prefetch, B chunked.
// Round-5 post-mortem: full A+B double-buffer needs 320 unified regs > 256
// -> 800MB scratch spills, gain erased. Register arithmetic from r3/r5:
// arch-VGPR live set in r3 is ~100/128, so prefetch budget is ~32 regs.
// This round = round-3 structure (612us, best so far) with ONLY the K-loop
// changed: prefetch next A fragments (32 regs, hides ~200cyc L2 latency
// under the 32-MFMA block) and load B in two chunks of 4 (32 regs live,
// chunk loads hide under the other chunk's 16 MFMAs).

typedef _Float16 f16;
typedef _Float16 f16x8 __attribute__((ext_vector_type(8)));
typedef _Float16 f16x4 __attribute__((ext_vector_type(4)));
typedef float    f32x4 __attribute__((ext_vector_type(4)));

#define MFMA(a, b, c) __builtin_amdgcn_mfma_f32_16x16x32_f16((a), (b), (c), 0, 0, 0)

constexpr int HF = 64, WF = 64;         // feature map dims
constexpr int HO = 256, WO = 256;       // output dims
constexpr int Q = HO * WO;              // 65536 queries per image
constexpr int D = 256;                  // hidden width
constexpr int K0P = 96;                 // input dim 68 padded to 96 (3 k-steps)
constexpr int STR = 264;                // LDS row stride (halves)
constexpr int R = 128;                  // query rows per block

// workspace layout (bytes)
constexpr size_t OFF_FEAT = 0;                        // 4*4096*64*2 = 2 MiB
constexpr size_t OFF_W0   = 2097152;                  // 256*96*2
constexpr size_t OFF_W1   = OFF_W0 + 256 * 96 * 2;    // 256*256*2
constexpr size_t OFF_W2   = OFF_W1 + 256 * 256 * 2;
constexpr size_t OFF_W3   = OFF_W2 + 256 * 256 * 2;
constexpr size_t OFF_W4   = OFF_W3 + 256 * 256 * 2;   // 16*256*2

// (N,C,Hf,Wf) fp32 -> (N, Hf*Wf, C) fp16 so a gather row is 128 B contiguous.
__global__ void prep_feat(const float* __restrict__ f, f16* __restrict__ ft) {
  int idx = blockIdx.x * 256 + threadIdx.x;          // 1,048,576 total
  int c = idx & 63, p = (idx >> 6) & 4095, n = idx >> 18;
  ft[idx] = (f16)f[((((size_t)n << 6) | c) << 12) | p];
}

// w (K x N) fp32 -> wt (Npad x Kpad) fp16, zero-padded.
__global__ void prep_w(const float* __restrict__ w, f16* __restrict__ wt,
                       int K, int N, int Kpad, int Npad) {
  int idx = blockIdx.x * 256 + threadIdx.x;
  if (idx >= Npad * Kpad) return;
  int k = idx % Kpad, n = idx / Kpad;
  wt[idx] = (f16)((k < K && n < N) ? w[k * N + n] : 0.0f);
}

// Geometry for query q, tap (vx, vy): feature pixel p and rel coords.
__device__ __forceinline__ void tap_geom(int q, float vx, float vy,
                                         int& p, float& rel0, float& rel1) {
  int qy = q >> 8, qx = q & (WO - 1);
  float cy0 = (float)(2 * qy + 1) * (1.0f / HO) - 1.0f;
  float cx0 = (float)(2 * qx + 1) * (1.0f / WO) - 1.0f;
  float cy = cy0 + vx * (1.0f / HF) + 1e-6f;
  float cx = cx0 + vy * (1.0f / WF) + 1e-6f;
  cy = fminf(fmaxf(cy, -1.0f + 1e-6f), 1.0f - 1e-6f);
  cx = fminf(fmaxf(cx, -1.0f + 1e-6f), 1.0f - 1e-6f);
  int iy = (int)rintf(((cy + 1.0f) * (float)HF - 1.0f) * 0.5f);  // rndne == jnp.round
  int ix = (int)rintf(((cx + 1.0f) * (float)WF - 1.0f) * 0.5f);
  iy = min(max(iy, 0), HF - 1);
  ix = min(max(ix, 0), WF - 1);
  p = (iy << 6) | ix;
  rel0 = (cy0 - ((float)(2 * iy + 1) * (1.0f / HF) - 1.0f)) * (float)HF;
  rel1 = (cx0 - ((float)(2 * ix + 1) * (1.0f / WF) - 1.0f)) * (float)WF;
}

// Blend weight for tap t, query q: preds[t] pairs with areas[3-t].
__device__ __forceinline__ float blend_wt(int q, int t) {
  float a[4], tot = 0.0f;
#pragma unroll
  for (int u = 0; u < 4; ++u) {
    int p; float r0, r1;
    tap_geom(q, (u & 2) ? 1.0f : -1.0f, (u & 1) ? 1.0f : -1.0f, p, r0, r1);
    a[u] = fabsf(r0 * r1) + 1e-9f;
    tot += a[u];
  }
  float sel = (t == 0) ? a[3] : (t == 1) ? a[2] : (t == 2) ? a[1] : a[0];
  return sel / tot;
}

// One hidden layer on the shared 128-row tile, in place.
// m = out-feature (wave wv owns feats [wv*64, wv*64+64)), n = all 128 queries.
// A (weights, L2) prefetched one K-step ahead; B (LDS) in two chunks of 4.
template <int KSTEPS, int KPAD>
__device__ __forceinline__ void mlp_layer(f16* X, const f16* __restrict__ wt,
                                          const float* __restrict__ bv,
                                          int wv, int col, int quad) {
  f32x4 acc[4][8];
#pragma unroll
  for (int mt = 0; mt < 4; ++mt)
#pragma unroll
    for (int nt = 0; nt < 8; ++nt) acc[mt][nt] = 0.0f;

  const f16* ap = wt + (wv * 64 + col) * KPAD + quad * 8;  // A[m=col+16mt][k]
  const f16* bp = X + col * STR + quad * 8;                // B[n=col+16nt][k]

  f16x8 a[4], an[4];
#pragma unroll
  for (int mt = 0; mt < 4; ++mt) a[mt] = *(const f16x8*)(ap + mt * 16 * KPAD);

#pragma unroll 1
  for (int s = 0; s < KSTEPS; ++s) {
    if (s + 1 < KSTEPS) {
#pragma unroll
      for (int mt = 0; mt < 4; ++mt)
        an[mt] = *(const f16x8*)(ap + (s + 1) * 32 + mt * 16 * KPAD);
    }
#pragma unroll
    for (int half = 0; half < 2; ++half) {
      f16x8 b[4];
#pragma unroll
      for (int nt = 0; nt < 4; ++nt)
        b[nt] = *(const f16x8*)(bp + s * 32 + (half * 4 + nt) * 16 * STR);
#pragma unroll
      for (int mt = 0; mt < 4; ++mt)
#pragma unroll
        for (int nt = 0; nt < 4; ++nt)
          acc[mt][half * 4 + nt] = MFMA(a[mt], b[nt], acc[mt][half * 4 + nt]);
    }
#pragma unroll
    for (int mt = 0; mt < 4; ++mt) a[mt] = an[mt];
  }

  __syncthreads();   // all reads of X done before overwrite
  // D: row(m=feat) = mt*16 + quad*4 + i, col(n=query) = nt*16 + col.
#pragma unroll
  for (int mt = 0; mt < 4; ++mt) {
    float4 bb = *(const float4*)(bv + wv * 64 + mt * 16 + quad * 4);
#pragma unroll
    for (int nt = 0; nt < 8; ++nt) {
      f16x4 y;
      y[0] = (f16)fmaxf(acc[mt][nt][0] + bb.x, 0.0f);
      y[1] = (f16)fmaxf(acc[mt][nt][1] + bb.y, 0.0f);
      y[2] = (f16)fmaxf(acc[mt][nt][2] + bb.z, 0.0f);
      y[3] = (f16)fmaxf(acc[mt][nt][3] + bb.w, 0.0f);
      *(f16x4*)(X + (nt * 16 + col) * STR + wv * 64 + mt * 16 + quad * 4) = y;
    }
  }
  __syncthreads();
}

__global__ __launch_bounds__(256, 2) void liif_main(
    const f16* __restrict__ featT,
    const f16* __restrict__ wt0, const f16* __restrict__ wt1,
    const f16* __restrict__ wt2, const f16* __restrict__ wt3,
    const f16* __restrict__ wt4,
    const float* __restrict__ b0, const float* __restrict__ b1,
    const float* __restrict__ b2, const float* __restrict__ b3,
    const float* __restrict__ b4, float* __restrict__ out) {
  __shared__ __attribute__((aligned(16))) f16 X[R * STR];   // 67.6 KB
  const int tid = threadIdx.x;
  const int wv = tid >> 6;
  const int lane = tid & 63;
  const int row0 = blockIdx.x * R;               // rows = n*Q + q, 128 per block
  const int n = row0 >> 16;
  const int q0 = row0 & (Q - 1);
  const int col = lane & 15, quad = lane >> 4;

  float oacc[2][4] = {{0, 0, 0, 0}, {0, 0, 0, 0}};
  float bias4[4];
#pragma unroll
  for (int i = 0; i < 4; ++i) bias4[i] = (i < 3) ? b4[i] : 0.0f;

#pragma unroll 1
  for (int t = 0; t < 4; ++t) {
    const float vx = (t & 2) ? 1.0f : -1.0f;
    const float vy = (t & 1) ? 1.0f : -1.0f;

    __syncthreads();   // previous tap's reads of X complete
    // ---- gather X0: 64 feat + rel(2) + rel_cell(2), pad to 96 ----
    {
      const int gr = tid >> 1, hf = tid & 1;   // 2 threads per row, 64 B each
      int p; float r0, r1;
      tap_geom(q0 + gr, vx, vy, p, r0, r1);
      const f16x8* src = (const f16x8*)(featT + (((size_t)n << 12) + p) * 64 + hf * 32);
      f16x8* dst = (f16x8*)(X + gr * STR + hf * 32);
      dst[0] = src[0]; dst[1] = src[1]; dst[2] = src[2]; dst[3] = src[3];
      if (tid < R) {
        int p2; float s0, s1;
        tap_geom(q0 + tid, vx, vy, p2, s0, s1);
        f16* xr = X + tid * STR;
        f16x4 relv = {(f16)s0, (f16)s1, (f16)0.5f, (f16)0.5f};
        *(f16x4*)(xr + 64) = relv;
        f16x4 z4 = {0, 0, 0, 0};
        f16x8 z8 = {0, 0, 0, 0, 0, 0, 0, 0};
        *(f16x4*)(xr + 68) = z4;     // zero pad cols 68..95
        *(f16x8*)(xr + 72) = z8;
        *(f16x8*)(xr + 80) = z8;
        *(f16x8*)(xr + 88) = z8;
      }
    }
    __syncthreads();

    mlp_layer<3, K0P>(X, wt0, b0, wv, col, quad);
    mlp_layer<8, D>(X, wt1, b1, wv, col, quad);
    mlp_layer<8, D>(X, wt2, b2, wv, col, quad);
    mlp_layer<8, D>(X, wt3, b3, wv, col, quad);

    // ---- final layer 256 -> 16 (3 real feats); wave handles its 32 queries ----
    f32x4 facc[2];
    facc[0] = 0.0f; facc[1] = 0.0f;
    {
      const f16* ap = wt4 + col * D + quad * 8;              // A[m=feat=col][k]
      const f16* bp = X + (wv * 32 + col) * STR + quad * 8;  // B[n=query]
#pragma unroll 1
      for (int s = 0; s < 8; ++s) {
        f16x8 a = *(const f16x8*)(ap + s * 32);
        f16x8 bq0 = *(const f16x8*)(bp + s * 32);
        f16x8 bq1 = *(const f16x8*)(bp + 16 * STR + s * 32);
        facc[0] = MFMA(a, bq0, facc[0]);
        facc[1] = MFMA(a, bq1, facc[1]);
      }
    }
    // D: row=feat=quad*4+i, col=query. Blend into oacc.
#pragma unroll
    for (int nt = 0; nt < 2; ++nt) {
      int q = q0 + wv * 32 + nt * 16 + col;
      float w = blend_wt(q, t);
#pragma unroll
      for (int i = 0; i < 4; ++i) oacc[nt][i] += (facc[nt][i] + bias4[i]) * w;
    }
  }

  // out[n][c][q]; lanes with quad==0 hold feats 0..3 (3 real) for their queries
  if (quad == 0) {
#pragma unroll
    for (int nt = 0; nt < 2; ++nt) {
      int q = q0 + wv * 32 + nt * 16 + col;
#pragma unroll
      for (int c = 0; c < 3; ++c)
        out[(((size_t)(n * 3 + c)) << 16) + q] = oacc[nt][c];
    }
  }
}

extern "C" void kernel_launch(void* const* d_in, const int* in_sizes, int n_in,
                              void* d_out, int out_size, void* d_ws, size_t ws_size,
                              hipStream_t stream) {
  const float* feat = (const float*)d_in[0];
  const float* w0 = (const float*)d_in[1];
  const float* b0 = (const float*)d_in[2];
  const float* w1 = (const float*)d_in[3];
  const float* b1 = (const float*)d_in[4];
  const float* w2 = (const float*)d_in[5];
  const float* b2 = (const float*)d_in[6];
  const float* w3 = (const float*)d_in[7];
  const float* b3 = (const float*)d_in[8];
  const float* w4 = (const float*)d_in[9];
  const float* b4 = (const float*)d_in[10];

  char* ws = (char*)d_ws;
  f16* featT = (f16*)(ws + OFF_FEAT);
  f16* wt0 = (f16*)(ws + OFF_W0);
  f16* wt1 = (f16*)(ws + OFF_W1);
  f16* wt2 = (f16*)(ws + OFF_W2);
  f16* wt3 = (f16*)(ws + OFF_W3);
  f16* wt4 = (f16*)(ws + OFF_W4);

  prep_feat<<<4096, 256, 0, stream>>>(feat, featT);
  prep_w<<<(256 * 96 + 255) / 256, 256, 0, stream>>>(w0, wt0, 68, 256, 96, 256);
  prep_w<<<256, 256, 0, stream>>>(w1, wt1, 256, 256, 256, 256);
  prep_w<<<256, 256, 0, stream>>>(w2, wt2, 256, 256, 256, 256);
  prep_w<<<256, 256, 0, stream>>>(w3, wt3, 256, 256, 256, 256);
  prep_w<<<(16 * 256 + 255) / 256, 256, 0, stream>>>(w4, wt4, 256, 3, 256, 16);

  liif_main<<<Q * 4 / R, 256, 0, stream>>>(featT, wt0, wt1, wt2, wt3, wt4,
                                           b0, b1, b2, b3, b4, (float*)d_out);
}

// Round 8
// 631.801 us; speedup vs baseline: 1.0532x; 1.0532x over previous
//
#include <hip/hip_runtime.h>

// LIIF render, fully fused, fp16 MFMA. Round 7: split acc across 2x waves.
// r5/r6 post-mortem: acc[4][8]=128 AGPR leaves ZERO arch-VGPR headroom at
// 2 waves/SIMD — every pipelining attempt spilled (247-800 MB scratch).
// The register file is fixed per SIMD (2x256 == 4x128), so get latency
// hiding from TLP instead: 512-thread blocks, 8 waves, each wave owns
// 32 out-features x 128 queries -> acc[2][8]=64 AGPR + ~46 arch = ~110
// of the 128-reg cap at __launch_bounds__(512,4) -> 4 waves/SIMD.
// Same 128-row block tile (weight L2 traffic unchanged, 3.6 GB); B-LDS
// reads double (B-reuse 2 not 4) — LDS pipe runs parallel to MFMA.

typedef _Float16 f16;
typedef _Float16 f16x8 __attribute__((ext_vector_type(8)));
typedef _Float16 f16x4 __attribute__((ext_vector_type(4)));
typedef float    f32x4 __attribute__((ext_vector_type(4)));

#define MFMA(a, b, c) __builtin_amdgcn_mfma_f32_16x16x32_f16((a), (b), (c), 0, 0, 0)

constexpr int HF = 64, WF = 64;         // feature map dims
constexpr int HO = 256, WO = 256;       // output dims
constexpr int Q = HO * WO;              // 65536 queries per image
constexpr int D = 256;                  // hidden width
constexpr int K0P = 96;                 // input dim 68 padded to 96 (3 k-steps)
constexpr int STR = 264;                // LDS row stride (halves)
constexpr int R = 128;                  // query rows per block

// workspace layout (bytes)
constexpr size_t OFF_FEAT = 0;                        // 4*4096*64*2 = 2 MiB
constexpr size_t OFF_W0   = 2097152;                  // 256*96*2
constexpr size_t OFF_W1   = OFF_W0 + 256 * 96 * 2;    // 256*256*2
constexpr size_t OFF_W2   = OFF_W1 + 256 * 256 * 2;
constexpr size_t OFF_W3   = OFF_W2 + 256 * 256 * 2;
constexpr size_t OFF_W4   = OFF_W3 + 256 * 256 * 2;   // 16*256*2

// (N,C,Hf,Wf) fp32 -> (N, Hf*Wf, C) fp16 so a gather row is 128 B contiguous.
__global__ void prep_feat(const float* __restrict__ f, f16* __restrict__ ft) {
  int idx = blockIdx.x * 256 + threadIdx.x;          // 1,048,576 total
  int c = idx & 63, p = (idx >> 6) & 4095, n = idx >> 18;
  ft[idx] = (f16)f[((((size_t)n << 6) | c) << 12) | p];
}

// w (K x N) fp32 -> wt (Npad x Kpad) fp16, zero-padded.
__global__ void prep_w(const float* __restrict__ w, f16* __restrict__ wt,
                       int K, int N, int Kpad, int Npad) {
  int idx = blockIdx.x * 256 + threadIdx.x;
  if (idx >= Npad * Kpad) return;
  int k = idx % Kpad, n = idx / Kpad;
  wt[idx] = (f16)((k < K && n < N) ? w[k * N + n] : 0.0f);
}

// Geometry for query q, tap (vx, vy): feature pixel p and rel coords.
__device__ __forceinline__ void tap_geom(int q, float vx, float vy,
                                         int& p, float& rel0, float& rel1) {
  int qy = q >> 8, qx = q & (WO - 1);
  float cy0 = (float)(2 * qy + 1) * (1.0f / HO) - 1.0f;
  float cx0 = (float)(2 * qx + 1) * (1.0f / WO) - 1.0f;
  float cy = cy0 + vx * (1.0f / HF) + 1e-6f;
  float cx = cx0 + vy * (1.0f / WF) + 1e-6f;
  cy = fminf(fmaxf(cy, -1.0f + 1e-6f), 1.0f - 1e-6f);
  cx = fminf(fmaxf(cx, -1.0f + 1e-6f), 1.0f - 1e-6f);
  int iy = (int)rintf(((cy + 1.0f) * (float)HF - 1.0f) * 0.5f);  // rndne == jnp.round
  int ix = (int)rintf(((cx + 1.0f) * (float)WF - 1.0f) * 0.5f);
  iy = min(max(iy, 0), HF - 1);
  ix = min(max(ix, 0), WF - 1);
  p = (iy << 6) | ix;
  rel0 = (cy0 - ((float)(2 * iy + 1) * (1.0f / HF) - 1.0f)) * (float)HF;
  rel1 = (cx0 - ((float)(2 * ix + 1) * (1.0f / WF) - 1.0f)) * (float)WF;
}

// Blend weight for tap t, query q: preds[t] pairs with areas[3-t].
__device__ __forceinline__ float blend_wt(int q, int t) {
  float a[4], tot = 0.0f;
#pragma unroll
  for (int u = 0; u < 4; ++u) {
    int p; float r0, r1;
    tap_geom(q, (u & 2) ? 1.0f : -1.0f, (u & 1) ? 1.0f : -1.0f, p, r0, r1);
    a[u] = fabsf(r0 * r1) + 1e-9f;
    tot += a[u];
  }
  float sel = (t == 0) ? a[3] : (t == 1) ? a[2] : (t == 2) ? a[1] : a[0];
  return sel / tot;
}

// One hidden layer on the shared 128-row tile, in place.
// Wave wv owns out-feats [wv*32, wv*32+32) (2 m-tiles), all 128 queries.
template <int KSTEPS, int KPAD>
__device__ __forceinline__ void mlp_layer(f16* X, const f16* __restrict__ wt,
                                          const float* __restrict__ bv,
                                          int wv, int col, int quad) {
  f32x4 acc[2][8];
#pragma unroll
  for (int mt = 0; mt < 2; ++mt)
#pragma unroll
    for (int nt = 0; nt < 8; ++nt) acc[mt][nt] = 0.0f;

  const f16* ap = wt + (wv * 32 + col) * KPAD + quad * 8;  // A[m=col+16mt][k]
  const f16* bp = X + col * STR + quad * 8;                // B[n=col+16nt][k]

#pragma unroll 1
  for (int s = 0; s < KSTEPS; ++s) {
    f16x8 a0 = *(const f16x8*)(ap + s * 32);
    f16x8 a1 = *(const f16x8*)(ap + s * 32 + 16 * KPAD);
#pragma unroll
    for (int half = 0; half < 2; ++half) {
      f16x8 b[4];
#pragma unroll
      for (int nt = 0; nt < 4; ++nt)
        b[nt] = *(const f16x8*)(bp + s * 32 + (half * 4 + nt) * 16 * STR);
#pragma unroll
      for (int nt = 0; nt < 4; ++nt) {
        acc[0][half * 4 + nt] = MFMA(a0, b[nt], acc[0][half * 4 + nt]);
        acc[1][half * 4 + nt] = MFMA(a1, b[nt], acc[1][half * 4 + nt]);
      }
    }
  }

  __syncthreads();   // all reads of X done before overwrite
  // D: row(m=feat) = mt*16 + quad*4 + i, col(n=query) = nt*16 + col.
#pragma unroll
  for (int mt = 0; mt < 2; ++mt) {
    float4 bb = *(const float4*)(bv + wv * 32 + mt * 16 + quad * 4);
#pragma unroll
    for (int nt = 0; nt < 8; ++nt) {
      f16x4 y;
      y[0] = (f16)fmaxf(acc[mt][nt][0] + bb.x, 0.0f);
      y[1] = (f16)fmaxf(acc[mt][nt][1] + bb.y, 0.0f);
      y[2] = (f16)fmaxf(acc[mt][nt][2] + bb.z, 0.0f);
      y[3] = (f16)fmaxf(acc[mt][nt][3] + bb.w, 0.0f);
      *(f16x4*)(X + (nt * 16 + col) * STR + wv * 32 + mt * 16 + quad * 4) = y;
    }
  }
  __syncthreads();
}

__global__ __launch_bounds__(512, 4) void liif_main(
    const f16* __restrict__ featT,
    const f16* __restrict__ wt0, const f16* __restrict__ wt1,
    const f16* __restrict__ wt2, const f16* __restrict__ wt3,
    const f16* __restrict__ wt4,
    const float* __restrict__ b0, const float* __restrict__ b1,
    const float* __restrict__ b2, const float* __restrict__ b3,
    const float* __restrict__ b4, float* __restrict__ out) {
  __shared__ __attribute__((aligned(16))) f16 X[R * STR];   // 67.6 KB
  const int tid = threadIdx.x;
  const int wv = tid >> 6;                       // 0..7
  const int lane = tid & 63;
  const int row0 = blockIdx.x * R;               // rows = n*Q + q, 128 per block
  const int n = row0 >> 16;
  const int q0 = row0 & (Q - 1);
  const int col = lane & 15, quad = lane >> 4;

  float oacc[4] = {0, 0, 0, 0};
  float bias4[4];
#pragma unroll
  for (int i = 0; i < 4; ++i) bias4[i] = (i < 3) ? b4[i] : 0.0f;

#pragma unroll 1
  for (int t = 0; t < 4; ++t) {
    const float vx = (t & 2) ? 1.0f : -1.0f;
    const float vy = (t & 1) ? 1.0f : -1.0f;

    __syncthreads();   // previous tap's reads of X complete
    // ---- gather X0: 64 feat + rel(2) + rel_cell(2), pad to 96 ----
    {
      const int gr = tid >> 2, part = tid & 3;   // 4 threads per row, 32 B each
      int p; float r0, r1;
      tap_geom(q0 + gr, vx, vy, p, r0, r1);
      const f16x8* src = (const f16x8*)(featT + (((size_t)n << 12) + p) * 64) + part * 2;
      f16x8* dst = (f16x8*)(X + gr * STR) + part * 2;
      dst[0] = src[0]; dst[1] = src[1];
      if (tid < R) {
        int p2; float s0, s1;
        tap_geom(q0 + tid, vx, vy, p2, s0, s1);
        f16* xr = X + tid * STR;
        f16x4 relv = {(f16)s0, (f16)s1, (f16)0.5f, (f16)0.5f};
        *(f16x4*)(xr + 64) = relv;
        f16x4 z4 = {0, 0, 0, 0};
        f16x8 z8 = {0, 0, 0, 0, 0, 0, 0, 0};
        *(f16x4*)(xr + 68) = z4;     // zero pad cols 68..95
        *(f16x8*)(xr + 72) = z8;
        *(f16x8*)(xr + 80) = z8;
        *(f16x8*)(xr + 88) = z8;
      }
    }
    __syncthreads();

    mlp_layer<3, K0P>(X, wt0, b0, wv, col, quad);
    mlp_layer<8, D>(X, wt1, b1, wv, col, quad);
    mlp_layer<8, D>(X, wt2, b2, wv, col, quad);
    mlp_layer<8, D>(X, wt3, b3, wv, col, quad);

    // ---- final layer 256 -> 16 (3 real feats); wave wv owns 16-query tile wv
    f32x4 facc = 0.0f;
    {
      const f16* ap = wt4 + col * D + quad * 8;              // A[m=feat=col][k]
      const f16* bp = X + (wv * 16 + col) * STR + quad * 8;  // B[n=query]
#pragma unroll 1
      for (int s = 0; s < 8; ++s) {
        f16x8 a = *(const f16x8*)(ap + s * 32);
        f16x8 b = *(const f16x8*)(bp + s * 32);
        facc = MFMA(a, b, facc);
      }
    }
    // D: row=feat=quad*4+i, col=query. Blend into oacc.
    {
      int q = q0 + wv * 16 + col;
      float w = blend_wt(q, t);
#pragma unroll
      for (int i = 0; i < 4; ++i) oacc[i] += (facc[i] + bias4[i]) * w;
    }
  }

  // out[n][c][q]; lanes with quad==0 hold feats 0..3 (3 real) for their query
  if (quad == 0) {
    int q = q0 + wv * 16 + col;
#pragma unroll
    for (int c = 0; c < 3; ++c)
      out[(((size_t)(n * 3 + c)) << 16) + q] = oacc[c];
  }
}

extern "C" void kernel_launch(void* const* d_in, const int* in_sizes, int n_in,
                              void* d_out, int out_size, void* d_ws, size_t ws_size,
                              hipStream_t stream) {
  const float* feat = (const float*)d_in[0];
  const float* w0 = (const float*)d_in[1];
  const float* b0 = (const float*)d_in[2];
  const float* w1 = (const float*)d_in[3];
  const float* b1 = (const float*)d_in[4];
  const float* w2 = (const float*)d_in[5];
  const float* b2 = (const float*)d_in[6];
  const float* w3 = (const float*)d_in[7];
  const float* b3 = (const float*)d_in[8];
  const float* w4 = (const float*)d_in[9];
  const float* b4 = (const float*)d_in[10];

  char* ws = (char*)d_ws;
  f16* featT = (f16*)(ws + OFF_FEAT);
  f16* wt0 = (f16*)(ws + OFF_W0);
  f16* wt1 = (f16*)(ws + OFF_W1);
  f16* wt2 = (f16*)(ws + OFF_W2);
  f16* wt3 = (f16*)(ws + OFF_W3);
  f16* wt4 = (f16*)(ws + OFF_W4);

  prep_feat<<<4096, 256, 0, stream>>>(feat, featT);
  prep_w<<<(256 * 96 + 255) / 256, 256, 0, stream>>>(w0, wt0, 68, 256, 96, 256);
  prep_w<<<256, 256, 0, stream>>>(w1, wt1, 256, 256, 256, 256);
  prep_w<<<256, 256, 0, stream>>>(w2, wt2, 256, 256, 256, 256);
  prep_w<<<256, 256, 0, stream>>>(w3, wt3, 256, 256, 256, 256);
  prep_w<<<(16 * 256 + 255) / 256, 256, 0, stream>>>(w4, wt4, 256, 3, 256, 16);

  liif_main<<<Q * 4 / R, 512, 0, stream>>>(featT, wt0, wt1, wt2, wt3, wt4,
                                           b0, b1, b2, b3, b4, (float*)d_out);
}